// Round 7
// baseline (395.493 us; speedup 1.0000x reference)
//
#include <hip/hip_runtime.h>

typedef _Float16 f16;
typedef _Float16 f16x4 __attribute__((ext_vector_type(4)));
typedef _Float16 f16x8 __attribute__((ext_vector_type(8)));
typedef __fp16   h16x2 __attribute__((ext_vector_type(2)));
typedef float    f32x4 __attribute__((ext_vector_type(4)));

struct h16x2x2 { h16x2 lo, hi; };

#define MFMA16(a,b,c) __builtin_amdgcn_mfma_f32_16x16x32_f16((a),(b),(c),0,0,0)

#define LATENT 64
#define HIDDEN 128

// Barrier that orders LDS only: waits this wave's ds ops, then s_barrier.
__device__ __forceinline__ void bar_lds() {
  asm volatile("s_waitcnt lgkmcnt(0)\n\ts_barrier" ::: "memory");
}
// Intra-wave LDS write->read fence (no barrier).
__device__ __forceinline__ void fence_lds() {
  asm volatile("s_waitcnt lgkmcnt(0)" ::: "memory");
}

// A-fragment of W[out][K] for out-tile `tile`, k-chunk kf (32 wide).
// mfma_f32_16x16x32_f16 A layout: row = lane%16, k = kf*32 + 8*(lane/16)+j
__device__ __forceinline__ f16x8 load_afrag(const float* __restrict__ W, int K,
                                            int tile, int kf, int lane) {
  const int row = tile * 16 + (lane & 15);
  const int k0  = kf * 32 + (lane >> 4) * 8;
  const float* p = W + row * K + k0;
  f16x8 r;
#pragma unroll
  for (int j = 0; j < 8; ++j) r[j] = (f16)p[j];
  return r;
}

// B-fragment from LDS activation tile [16 rows][dims] f16, XOR-swizzled rows.
__device__ __forceinline__ f16x8 bfrag(const f16* buf, int rowb, int k0, int lane) {
  const int b  = lane & 15;
  const int kk = k0 + (lane >> 4) * 8;
  const int off = b * rowb + ((kk * 2) ^ ((b & 7) << 4));
  return *(const f16x8*)((const char*)buf + off);
}

// Write one D-tile (f32x4 -> f16x4, packed RTZ cvt) into an activation buffer.
__device__ __forceinline__ void dwrite(f16* buf, int rowb, int dbase, f32x4 v, int lane) {
  const int b = lane & 15;
  h16x2x2 p;
  p.lo = __builtin_amdgcn_cvt_pkrtz(v[0], v[1]);
  p.hi = __builtin_amdgcn_cvt_pkrtz(v[2], v[3]);
  const f16x4 h = __builtin_bit_cast(f16x4, p);
  const int off = b * rowb + ((dbase * 2) ^ ((b & 7) << 4));
  *(f16x4*)((char*)buf + off) = h;
}

__device__ __forceinline__ f32x4 elu4(f32x4 d) {
#pragma unroll
  for (int i = 0; i < 4; ++i) {
    const float e = __expf(d[i]) - 1.f;
    d[i] = d[i] > 0.f ? d[i] : e;
  }
  return d;
}

__global__ __launch_bounds__(256, 1)
void node_rk4_kernel(const float* __restrict__ z0,   const float* __restrict__ tg,
                     const float* __restrict__ fc1w, const float* __restrict__ fc1b,
                     const float* __restrict__ fc2w, const float* __restrict__ fc2b,
                     const float* __restrict__ fc3w, const float* __restrict__ fc3b,
                     const float* __restrict__ l2hw, const float* __restrict__ l2hb,
                     const float* __restrict__ h2ow, const float* __restrict__ h2ob,
                     float* __restrict__ out, int Btot, int T) {
  __shared__ __align__(16) f16 privx[4][16 * 64];  // per-wave private x staging
  __shared__ __align__(16) f16 h1buf[16 * 128];    // fc1 hidden (split across waves)
  __shared__ __align__(16) f16 h2buf[16 * 128];    // fc2 hidden (split across waves)
  __shared__ __align__(16) f16 dch1[16 * 128];     // decoder hidden (split)

  const int tid  = threadIdx.x;
  const int lane = tid & 63;
  const int wv   = tid >> 6;   // 0..3; l1/l2/dec split by wv; l3 fully redundant
  const int grp  = lane >> 4;
  const int bcol = lane & 15;
  const int row0 = blockIdx.x * 16;
  const f32x4 Z0 = {0.f, 0.f, 0.f, 0.f};
  f16* px = privx[wv];

  // ---- weights -> registers ----
  f16x8 a1[2][2], aL[2][2], a2[2][4], a3[4][4], aO[4];
  f32x4 b1[2], b2[2], bL[2], b3[4], bO;
#pragma unroll
  for (int ot = 0; ot < 2; ++ot) {
#pragma unroll
    for (int kf = 0; kf < 2; ++kf) {
      a1[ot][kf] = load_afrag(fc1w, 64, 2 * wv + ot, kf, lane);
      aL[ot][kf] = load_afrag(l2hw, 64, 2 * wv + ot, kf, lane);
    }
#pragma unroll
    for (int kf = 0; kf < 4; ++kf) a2[ot][kf] = load_afrag(fc2w, 128, 2 * wv + ot, kf, lane);
    const int d = (2 * wv + ot) * 16 + grp * 4;
    b1[ot] = *(const f32x4*)(fc1b + d);
    b2[ot] = *(const f32x4*)(fc2b + d);
    bL[ot] = *(const f32x4*)(l2hb + d);
  }
#pragma unroll
  for (int t = 0; t < 4; ++t) {
#pragma unroll
    for (int kf = 0; kf < 4; ++kf) a3[t][kf] = load_afrag(fc3w, 128, t, kf, lane);
    b3[t] = *(const f32x4*)(fc3b + t * 16 + grp * 4);
  }
  const int dz = wv * 16 + grp * 4;
#pragma unroll
  for (int kf = 0; kf < 4; ++kf) aO[kf] = load_afrag(h2ow, 128, wv, kf, lane);
  bO = *(const f32x4*)(h2ob + dz);

  // ---- z state: FULL per wave; lane holds z[16t+4g+i][bcol] ----
  f32x4 z[4];
#pragma unroll
  for (int t = 0; t < 4; ++t)
    z[t] = *(const f32x4*)(z0 + (size_t)(row0 + bcol) * LATENT + t * 16 + grp * 4);

  f16x8 zf0, zf1;  // B-frags of current z (rebuilt each step)
  auto stage_and_frag = [&](const f32x4 x[4], f16x8& f0, f16x8& f1) {
#pragma unroll
    for (int t = 0; t < 4; ++t) dwrite(px, 128, t * 16 + grp * 4, x[t], lane);
    fence_lds();  // intra-wave write->read
    f0 = bfrag(px, 128, 0, lane);
    f1 = bfrag(px, 128, 32, lane);
  };

  auto l1 = [&](f16x8 v0, f16x8 v1) {      // -> h1buf (split, fc1+elu)
#pragma unroll
    for (int ot = 0; ot < 2; ++ot) {
      f32x4 d = MFMA16(a1[ot][0], v0, b1[ot]);
      d = MFMA16(a1[ot][1], v1, d);
      d = elu4(d);
      dwrite(h1buf, 256, (2 * wv + ot) * 16 + grp * 4, d, lane);
    }
  };
  auto l2 = [&]() {                        // h1buf -> h2buf (split, fc2+elu)
    f16x8 h[4];
#pragma unroll
    for (int kf = 0; kf < 4; ++kf) h[kf] = bfrag(h1buf, 256, kf * 32, lane);
#pragma unroll
    for (int ot = 0; ot < 2; ++ot) {
      f32x4 c0 = MFMA16(a2[ot][0], h[0], b2[ot]);
      c0 = MFMA16(a2[ot][1], h[1], c0);
      f32x4 c1 = MFMA16(a2[ot][2], h[2], Z0);
      c1 = MFMA16(a2[ot][3], h[3], c1);
      f32x4 d = elu4(c0 + c1);
      dwrite(h2buf, 256, (2 * wv + ot) * 16 + grp * 4, d, lane);
    }
  };
  auto l3full = [&](f32x4 k[4]) {          // h2buf -> k (FULL, fc3, redundant/wave)
    f16x8 g[4];
#pragma unroll
    for (int kf = 0; kf < 4; ++kf) g[kf] = bfrag(h2buf, 256, kf * 32, lane);
#pragma unroll
    for (int t = 0; t < 4; ++t) {
      f32x4 c0 = MFMA16(a3[t][0], g[0], b3[t]);
      c0 = MFMA16(a3[t][1], g[1], c0);
      f32x4 c1 = MFMA16(a3[t][2], g[2], Z0);
      c1 = MFMA16(a3[t][3], g[3], c1);
      k[t] = c0 + c1;
    }
  };

  stage_and_frag(z, zf0, zf1);  // prologue

  float t_cur = tg[0];
  float t_nxt = tg[1];
  for (int s = 0;; ++s) {
    const bool last = (s == T - 1);

    // SEG1: dec-l1 (l2h+relu) + k1-l1 — both consume zf
#pragma unroll
    for (int ot = 0; ot < 2; ++ot) {
      f32x4 d = MFMA16(aL[ot][0], zf0, bL[ot]);
      d = MFMA16(aL[ot][1], zf1, d);
#pragma unroll
      for (int i = 0; i < 4; ++i) d[i] = fmaxf(d[i], 0.f);
      dwrite(dch1, 256, (2 * wv + ot) * 16 + grp * 4, d, lane);
    }
    if (!last) l1(zf0, zf1);
    bar_lds();                                       // BAR1

    // SEG2: dec-l2 (h2o) + store + k1-l2
    {
      f16x8 hd[4];
#pragma unroll
      for (int kf = 0; kf < 4; ++kf) hd[kf] = bfrag(dch1, 256, kf * 32, lane);
      f32x4 c0 = MFMA16(aO[0], hd[0], bO);
      c0 = MFMA16(aO[1], hd[1], c0);
      f32x4 c1 = MFMA16(aO[2], hd[2], Z0);
      c1 = MFMA16(aO[3], hd[3], c1);
      f32x4 o = c0 + c1;
      *(f32x4*)(out + ((size_t)s * Btot + row0 + bcol) * LATENT + dz) = o;
      if (!last) l2();
    }
    if (last) break;
    bar_lds();                                       // BAR2

    const float t_fut = tg[s + 2 < T ? s + 2 : T - 1];
    const float dt = t_nxt - t_cur;
    f32x4 k[4], acc[4], xs[4];
    f16x8 xf0, xf1;

    // SEG3: k1-l3(full) + update + private stage + k2-l1
    l3full(k);
#pragma unroll
    for (int t = 0; t < 4; ++t) {
      acc[t] = k[t];
#pragma unroll
      for (int i = 0; i < 4; ++i) xs[t][i] = z[t][i] + 0.5f * dt * k[t][i];
    }
    stage_and_frag(xs, xf0, xf1);
    l1(xf0, xf1);
    bar_lds();                                       // BAR3
    l2();
    bar_lds();                                       // BAR4

    // SEG5: k2-l3(full) + update + stage + k3-l1
    l3full(k);
#pragma unroll
    for (int t = 0; t < 4; ++t)
#pragma unroll
      for (int i = 0; i < 4; ++i) {
        acc[t][i] += 2.f * k[t][i];
        xs[t][i] = z[t][i] + 0.5f * dt * k[t][i];
      }
    stage_and_frag(xs, xf0, xf1);
    l1(xf0, xf1);
    bar_lds();                                       // BAR5
    l2();
    bar_lds();                                       // BAR6

    // SEG7: k3-l3(full) + update + stage + k4-l1
    l3full(k);
#pragma unroll
    for (int t = 0; t < 4; ++t)
#pragma unroll
      for (int i = 0; i < 4; ++i) {
        acc[t][i] += 2.f * k[t][i];
        xs[t][i] = z[t][i] + dt * k[t][i];
      }
    stage_and_frag(xs, xf0, xf1);
    l1(xf0, xf1);
    bar_lds();                                       // BAR7
    l2();
    bar_lds();                                       // BAR8

    // SEG9: k4-l3(full) + z update + stage z (flows into next SEG1, no barrier)
    l3full(k);
#pragma unroll
    for (int t = 0; t < 4; ++t)
#pragma unroll
      for (int i = 0; i < 4; ++i) z[t][i] += (dt / 6.f) * (acc[t][i] + k[t][i]);
    stage_and_frag(z, zf0, zf1);

    t_cur = t_nxt;
    t_nxt = t_fut;
  }
}

extern "C" void kernel_launch(void* const* d_in, const int* in_sizes, int n_in,
                              void* d_out, int out_size, void* d_ws, size_t ws_size,
                              hipStream_t stream) {
  const float* z0   = (const float*)d_in[0];
  const float* tg   = (const float*)d_in[1];
  const float* fc1w = (const float*)d_in[2];
  const float* fc1b = (const float*)d_in[3];
  const float* fc2w = (const float*)d_in[4];
  const float* fc2b = (const float*)d_in[5];
  const float* fc3w = (const float*)d_in[6];
  const float* fc3b = (const float*)d_in[7];
  const float* l2hw = (const float*)d_in[8];
  const float* l2hb = (const float*)d_in[9];
  const float* h2ow = (const float*)d_in[10];
  const float* h2ob = (const float*)d_in[11];
  float* out = (float*)d_out;

  const int Btot = in_sizes[0] / LATENT;  // 4096
  const int T    = in_sizes[1];           // 100

  dim3 grid(Btot / 16), block(256);
  node_rk4_kernel<<<grid, block, 0, stream>>>(z0, tg, fc1w, fc1b, fc2w, fc2b,
                                              fc3w, fc3b, l2hw, l2hb, h2ow, h2ob,
                                              out, Btot, T);
}

// Round 8
// 298.229 us; speedup vs baseline: 1.3261x; 1.3261x over previous
//
#include <hip/hip_runtime.h>

typedef _Float16 f16;
typedef _Float16 f16x4 __attribute__((ext_vector_type(4)));
typedef _Float16 f16x8 __attribute__((ext_vector_type(8)));
typedef __fp16   h16x2 __attribute__((ext_vector_type(2)));
typedef float    f32x4 __attribute__((ext_vector_type(4)));

struct h16x2x2 { h16x2 lo, hi; };

#define MFMA16(a,b,c) __builtin_amdgcn_mfma_f32_16x16x32_f16((a),(b),(c),0,0,0)

#define LATENT 64
#define HIDDEN 128
// LDS activation row pitch: 17 x 16B = 272B. Row index rotates the bank phase
// ((b*272/16) mod 8 = b mod 8), so a wave's 64 b128 lanes spread uniformly over
// all banks -> zero conflict serialization (vs 128/256B pitch: >=4-way).
#define ROWB  272
#define ROWF  (ROWB / 2)   // 136 f16 per row

// Barrier that orders LDS only: waits this wave's ds ops, then s_barrier.
// No vmcnt drain -> global stores never block the barrier.
__device__ __forceinline__ void bar_lds() {
  asm volatile("s_waitcnt lgkmcnt(0)\n\ts_barrier" ::: "memory");
}

// A-fragment of W[out][K] for out-tile `tile`, k-chunk kf (32 wide).
// mfma_f32_16x16x32_f16 A layout: row = lane%16, k = kf*32 + 8*(lane/16)+j
__device__ __forceinline__ f16x8 load_afrag(const float* __restrict__ W, int K,
                                            int tile, int kf, int lane) {
  const int row = tile * 16 + (lane & 15);
  const int k0  = kf * 32 + (lane >> 4) * 8;
  const float* p = W + row * K + k0;
  f16x8 r;
#pragma unroll
  for (int j = 0; j < 8; ++j) r[j] = (f16)p[j];
  return r;
}

// B-fragment from LDS activation tile: row b = lane%16 (batch), linear cols.
__device__ __forceinline__ f16x8 bfrag(const f16* buf, int k0, int lane) {
  const int b  = lane & 15;
  const int kk = k0 + (lane >> 4) * 8;
  return *(const f16x8*)((const char*)buf + b * ROWB + kk * 2);
}

// Write one D-tile (f32x4 -> f16x4, packed RTZ cvt) into an activation buffer.
__device__ __forceinline__ void dwrite(f16* buf, int dbase, f32x4 v, int lane) {
  const int b = lane & 15;
  h16x2x2 p;
  p.lo = __builtin_amdgcn_cvt_pkrtz(v[0], v[1]);
  p.hi = __builtin_amdgcn_cvt_pkrtz(v[2], v[3]);
  const f16x4 h = __builtin_bit_cast(f16x4, p);
  *(f16x4*)((char*)buf + b * ROWB + dbase * 2) = h;
}

__device__ __forceinline__ f32x4 elu4(f32x4 d) {
#pragma unroll
  for (int i = 0; i < 4; ++i) {
    const float e = __expf(d[i]) - 1.f;
    d[i] = d[i] > 0.f ? d[i] : e;
  }
  return d;
}

__global__ __launch_bounds__(256, 2)
void node_rk4_kernel(const float* __restrict__ z0,   const float* __restrict__ tg,
                     const float* __restrict__ fc1w, const float* __restrict__ fc1b,
                     const float* __restrict__ fc2w, const float* __restrict__ fc2b,
                     const float* __restrict__ fc3w, const float* __restrict__ fc3b,
                     const float* __restrict__ l2hw, const float* __restrict__ l2hb,
                     const float* __restrict__ h2ow, const float* __restrict__ h2ob,
                     float* __restrict__ out, int Btot, int T) {
  __shared__ __align__(16) f16 xbuf[16 * ROWF];   // f-input / z staging
  __shared__ __align__(16) f16 h1buf[16 * ROWF];  // fc1 hidden
  __shared__ __align__(16) f16 h2buf[16 * ROWF];  // fc2 hidden
  __shared__ __align__(16) f16 dch1[16 * ROWF];   // decoder hidden (l2h)

  const int tid  = threadIdx.x;
  const int lane = tid & 63;
  const int wv   = tid >> 6;   // 0..3; owns hidden tiles {2wv,2wv+1}, latent tile wv
  const int grp  = lane >> 4;
  const int bcol = lane & 15;
  const int row0 = blockIdx.x * 16;
  const f32x4 Z0 = {0.f, 0.f, 0.f, 0.f};

  // ---- weights -> registers (per-wave slices) ----
  f16x8 a1[2][2], aL[2][2], a2[2][4], a3[4], aO[4];
  f32x4 b1[2], b2[2], bL[2], b3, bO;
#pragma unroll
  for (int ot = 0; ot < 2; ++ot) {
#pragma unroll
    for (int kf = 0; kf < 2; ++kf) {
      a1[ot][kf] = load_afrag(fc1w, 64, 2 * wv + ot, kf, lane);
      aL[ot][kf] = load_afrag(l2hw, 64, 2 * wv + ot, kf, lane);
    }
#pragma unroll
    for (int kf = 0; kf < 4; ++kf) a2[ot][kf] = load_afrag(fc2w, 128, 2 * wv + ot, kf, lane);
    const int d = (2 * wv + ot) * 16 + grp * 4;
    b1[ot] = *(const f32x4*)(fc1b + d);
    b2[ot] = *(const f32x4*)(fc2b + d);
    bL[ot] = *(const f32x4*)(l2hb + d);
  }
#pragma unroll
  for (int kf = 0; kf < 4; ++kf) {
    a3[kf] = load_afrag(fc3w, 128, wv, kf, lane);
    aO[kf] = load_afrag(h2ow, 128, wv, kf, lane);
  }
  const int dz = wv * 16 + grp * 4;
  b3 = *(const f32x4*)(fc3b + dz);
  bO = *(const f32x4*)(h2ob + dz);

  // ---- z state: lane holds z[row0+bcol][dz..dz+3] (D layout) ----
  f32x4 z = *(const f32x4*)(z0 + (size_t)(row0 + bcol) * LATENT + dz);

  // layer pieces (no internal barriers; caller places bar_lds between)
  auto l1 = [&](f16x8 v0, f16x8 v1) {     // xbuf frags -> h1buf (fc1+elu)
#pragma unroll
    for (int ot = 0; ot < 2; ++ot) {
      f32x4 d = MFMA16(a1[ot][0], v0, b1[ot]);
      d = MFMA16(a1[ot][1], v1, d);
      d = elu4(d);
      dwrite(h1buf, (2 * wv + ot) * 16 + grp * 4, d, lane);
    }
  };
  auto l2 = [&]() {                       // h1buf -> h2buf (fc2+elu)
    f16x8 h[4];
#pragma unroll
    for (int kf = 0; kf < 4; ++kf) h[kf] = bfrag(h1buf, kf * 32, lane);
#pragma unroll
    for (int ot = 0; ot < 2; ++ot) {
      f32x4 c0 = MFMA16(a2[ot][0], h[0], b2[ot]);
      c0 = MFMA16(a2[ot][1], h[1], c0);
      f32x4 c1 = MFMA16(a2[ot][2], h[2], Z0);
      c1 = MFMA16(a2[ot][3], h[3], c1);
      f32x4 d = elu4(c0 + c1);
      dwrite(h2buf, (2 * wv + ot) * 16 + grp * 4, d, lane);
    }
  };
  auto l3 = [&]() -> f32x4 {              // h2buf -> k (fc3, own 16 latent dims)
    f16x8 g[4];
#pragma unroll
    for (int kf = 0; kf < 4; ++kf) g[kf] = bfrag(h2buf, kf * 32, lane);
    f32x4 c0 = MFMA16(a3[0], g[0], b3);
    c0 = MFMA16(a3[1], g[1], c0);
    f32x4 c1 = MFMA16(a3[2], g[2], Z0);
    c1 = MFMA16(a3[3], g[3], c1);
    return c0 + c1;
  };
  auto dec2_store = [&](int s) {          // dch1 -> h2o -> global store
    f16x8 hd[4];
#pragma unroll
    for (int kf = 0; kf < 4; ++kf) hd[kf] = bfrag(dch1, kf * 32, lane);
    f32x4 c0 = MFMA16(aO[0], hd[0], bO);
    c0 = MFMA16(aO[1], hd[1], c0);
    f32x4 c1 = MFMA16(aO[2], hd[2], Z0);
    c1 = MFMA16(aO[3], hd[3], c1);
    f32x4 o = c0 + c1;
    *(f32x4*)(out + ((size_t)s * Btot + row0 + bcol) * LATENT + dz) = o;
  };

  // prologue: stage z_0
  dwrite(xbuf, dz, z, lane);
  bar_lds();

  float t_cur = tg[0];
  float t_nxt = tg[1];
  for (int s = 0;; ++s) {
    const bool last = (s == T - 1);

    // SEG1: dec-l1 (l2h+relu) + k1-l1 — both consume xbuf
    {
      const f16x8 x0 = bfrag(xbuf, 0, lane);
      const f16x8 x1 = bfrag(xbuf, 32, lane);
#pragma unroll
      for (int ot = 0; ot < 2; ++ot) {
        f32x4 d = MFMA16(aL[ot][0], x0, bL[ot]);
        d = MFMA16(aL[ot][1], x1, d);
#pragma unroll
        for (int i = 0; i < 4; ++i) d[i] = fmaxf(d[i], 0.f);
        dwrite(dch1, (2 * wv + ot) * 16 + grp * 4, d, lane);
      }
      if (!last) l1(x0, x1);
    }
    bar_lds();                                       // BAR1

    if (last) { dec2_store(s); break; }

    // SEG2: k1-l2 only (decode tail moved to SEG3)
    l2();
    bar_lds();                                       // BAR2

    const float t_fut = tg[s + 2 < T ? s + 2 : T - 1];
    const float dt = t_nxt - t_cur;
    f32x4 k, acc, xs;

    // SEG3: dec-l2 + store + k1-l3 + stage x(k2)  (dch1/h2buf reads overlap)
    dec2_store(s);
    k = l3();
    acc = k;
#pragma unroll
    for (int i = 0; i < 4; ++i) xs[i] = z[i] + 0.5f * dt * k[i];
    dwrite(xbuf, dz, xs, lane);
    bar_lds();                                       // BAR3

    // ---- k2 ----
    { const f16x8 x0 = bfrag(xbuf, 0, lane), x1 = bfrag(xbuf, 32, lane);
      l1(x0, x1); }
    bar_lds();                                       // BAR4
    l2();
    bar_lds();                                       // BAR5
    k = l3();
#pragma unroll
    for (int i = 0; i < 4; ++i) { acc[i] += 2.f * k[i]; xs[i] = z[i] + 0.5f * dt * k[i]; }
    dwrite(xbuf, dz, xs, lane);
    bar_lds();                                       // BAR6

    // ---- k3 ----
    { const f16x8 x0 = bfrag(xbuf, 0, lane), x1 = bfrag(xbuf, 32, lane);
      l1(x0, x1); }
    bar_lds();                                       // BAR7
    l2();
    bar_lds();                                       // BAR8
    k = l3();
#pragma unroll
    for (int i = 0; i < 4; ++i) { acc[i] += 2.f * k[i]; xs[i] = z[i] + dt * k[i]; }
    dwrite(xbuf, dz, xs, lane);
    bar_lds();                                       // BAR9

    // ---- k4 ----
    { const f16x8 x0 = bfrag(xbuf, 0, lane), x1 = bfrag(xbuf, 32, lane);
      l1(x0, x1); }
    bar_lds();                                       // BAR10
    l2();
    bar_lds();                                       // BAR11
    k = l3();
#pragma unroll
    for (int i = 0; i < 4; ++i) z[i] += (dt / 6.f) * (acc[i] + k[i]);
    dwrite(xbuf, dz, z, lane);
    bar_lds();                                       // BAR12

    t_cur = t_nxt;
    t_nxt = t_fut;
  }
}

extern "C" void kernel_launch(void* const* d_in, const int* in_sizes, int n_in,
                              void* d_out, int out_size, void* d_ws, size_t ws_size,
                              hipStream_t stream) {
  const float* z0   = (const float*)d_in[0];
  const float* tg   = (const float*)d_in[1];
  const float* fc1w = (const float*)d_in[2];
  const float* fc1b = (const float*)d_in[3];
  const float* fc2w = (const float*)d_in[4];
  const float* fc2b = (const float*)d_in[5];
  const float* fc3w = (const float*)d_in[6];
  const float* fc3b = (const float*)d_in[7];
  const float* l2hw = (const float*)d_in[8];
  const float* l2hb = (const float*)d_in[9];
  const float* h2ow = (const float*)d_in[10];
  const float* h2ob = (const float*)d_in[11];
  float* out = (float*)d_out;

  const int Btot = in_sizes[0] / LATENT;  // 4096
  const int T    = in_sizes[1];           // 100

  dim3 grid(Btot / 16), block(256);
  node_rk4_kernel<<<grid, block, 0, stream>>>(z0, tg, fc1w, fc1b, fc2w, fc2b,
                                              fc3w, fc3b, l2hw, l2hb, h2ow, h2ob,
                                              out, Btot, T);
}